// Round 1
// baseline (574.705 us; speedup 1.0000x reference)
//
#include <hip/hip_runtime.h>

#define DEVI __device__ __forceinline__

// ---------- helpers ----------
DEVI unsigned fkey(float f) {             // order-preserving float->uint key
  unsigned u = __float_as_uint(f);
  return u ^ ((u >> 31) ? 0xFFFFFFFFu : 0x80000000u);
}
DEVI float funkey(unsigned k) {
  unsigned b = (k & 0x80000000u) ? (k ^ 0x80000000u) : ~k;
  return __uint_as_float(b);
}
DEVI float f4get(const float4& v, int j) {
  return j == 0 ? v.x : j == 1 ? v.y : j == 2 ? v.z : v.w;
}

// ================= CSR build: bucketed counting sort by dst =================
constexpr int BSH = 9;                 // 512 nodes per bucket
constexpr int BNODES = 1 << BSH;
constexpr int PEPT = 16;               // partition: edges per thread
constexpr int PCHUNK = 256 * PEPT;     // 4096 edges per block

__global__ void k_binit(int* __restrict__ bcnt) {
  bcnt[threadIdx.x] = 0;
}

__global__ void k_bcount(const int* __restrict__ dst, int* __restrict__ bcnt,
                         int E, int NB) {
  __shared__ int lh[256];
  lh[threadIdx.x] = 0;
  __syncthreads();
  int stride = gridDim.x * 256;
  for (long i = (long)blockIdx.x * 256 + threadIdx.x; i < E; i += stride)
    atomicAdd(&lh[dst[i] >> BSH], 1);
  __syncthreads();
  if (threadIdx.x < NB && lh[threadIdx.x]) atomicAdd(&bcnt[threadIdx.x], lh[threadIdx.x]);
}

__global__ void k_bscan(const int* __restrict__ bcnt, int* __restrict__ bbase,
                        int* __restrict__ bcur, unsigned* __restrict__ scal, int NB) {
  __shared__ int s[256];
  int t = threadIdx.x;
  int v = (t < NB) ? bcnt[t] : 0;
  s[t] = v;
  __syncthreads();
  for (int o = 1; o < 256; o <<= 1) {
    int add = (t >= o) ? s[t - o] : 0;
    __syncthreads();
    s[t] += add;
    __syncthreads();
  }
  int excl = s[t] - v;
  if (t < NB) { bbase[t] = excl; bcur[t] = excl; }
  if (t == 0) { scal[0] = 0u; scal[1] = 0u; }
}

// pack = (dst&511)<<17 | src  (requires N <= 2^17)
__global__ __launch_bounds__(256)
void k_bpart(const int* __restrict__ src, const int* __restrict__ dst,
             int* __restrict__ bcur, unsigned* __restrict__ epart, int E, int NB) {
  __shared__ int lh[256];
  __shared__ int gbase[256];
  long base = (long)blockIdx.x * PCHUNK;
  lh[threadIdx.x] = 0;
  __syncthreads();
  int ed[PEPT]; int es[PEPT]; unsigned short lpos[PEPT];
#pragma unroll
  for (int j = 0; j < PEPT; j++) {
    long i = base + threadIdx.x + (long)j * 256;   // coalesced
    if (i < E) {
      int d = dst[i];
      es[j] = src[i];
      ed[j] = d;
      lpos[j] = (unsigned short)atomicAdd(&lh[d >> BSH], 1);
    } else {
      ed[j] = -1;
    }
  }
  __syncthreads();
  if (threadIdx.x < NB) {
    int c = lh[threadIdx.x];
    gbase[threadIdx.x] = c ? atomicAdd(&bcur[threadIdx.x], c) : 0;
  }
  __syncthreads();
#pragma unroll
  for (int j = 0; j < PEPT; j++) {
    int d = ed[j];
    if (d >= 0) {
      unsigned p = (unsigned)(gbase[d >> BSH] + (int)lpos[j]);
      epart[p] = ((unsigned)(d & (BNODES - 1)) << 17) | (unsigned)es[j];
    }
  }
}

// one block per bucket: per-node hist + scan -> deg/rowptr/dinv, scatter col
__global__ __launch_bounds__(256)
void k_fine(const unsigned* __restrict__ epart, const int* __restrict__ bbase,
            const int* __restrict__ bcnt, int* __restrict__ rowptr,
            int* __restrict__ deg, float* __restrict__ dinv,
            int* __restrict__ col, int N) {
  __shared__ int lh[BNODES];
  __shared__ int lexcl[BNODES];
  __shared__ int ssc[256];
  int b = blockIdx.x;
  int base = bbase[b], cnt = bcnt[b];
  int nlo = b << BSH;
  int t = threadIdx.x;
  lh[t] = 0; lh[t + 256] = 0;
  __syncthreads();
  for (int i = t; i < cnt; i += 256) {
    unsigned e = epart[base + i];
    atomicAdd(&lh[e >> 17], 1);
  }
  __syncthreads();
  int a0 = lh[2 * t], a1 = lh[2 * t + 1];
  ssc[t] = a0 + a1;
  __syncthreads();
  for (int o = 1; o < 256; o <<= 1) {
    int add = (t >= o) ? ssc[t - o] : 0;
    __syncthreads();
    ssc[t] += add;
    __syncthreads();
  }
  int excl = ssc[t] - (a0 + a1);
  lexcl[2 * t] = excl;
  lexcl[2 * t + 1] = excl + a0;
  __syncthreads();
#pragma unroll
  for (int k = 0; k < 2; k++) {
    int i = t + k * 256;
    int v = nlo + i;
    if (v < N) {
      int dgv = lh[i];
      deg[v] = dgv;
      rowptr[v] = base + lexcl[i];
      dinv[v] = rsqrtf((float)(dgv + 1));
    }
  }
  __syncthreads();
  lh[2 * t] = lexcl[2 * t];
  lh[2 * t + 1] = lexcl[2 * t + 1];
  __syncthreads();
  for (int i = t; i < cnt; i += 256) {
    unsigned e = epart[base + i];
    int p = atomicAdd(&lh[e >> 17], 1);
    col[base + p] = (int)(e & 0x1FFFFu);
  }
}

// ---------- gemm1: x[Nx256] @ W1[256x32], scaled by dinv ----------
// R5 rewrite: issue-bound before (VALUBusy 22%, 8 ds_read_b128 per k-quad vs
// 32 FMA -> LDS reads ate the issue budget; split-K barrier+reduction added
// overhead without hiding latency). Now 4 cols x 4 rows per thread, full
// K=256: per k-quad = 4 independent global loads + 4 ds_read_b128 + 64 FMA
// (~70% of issue slots are FMA). 200k threads = 3125 waves = ~3/SIMD.
// LDS 32 KB (W only). unroll 2: 8 loads in flight, no VGPR spill.
__global__ __launch_bounds__(256)
void k_gemm1(const float* __restrict__ in, const float* __restrict__ W,
             const float* __restrict__ dinv, float* __restrict__ out, int N) {
  __shared__ float Wl[256 * 32];      // 32 KB
  {
    const float4* W4 = (const float4*)W;
    float4* Wl4 = (float4*)Wl;
    for (int i = threadIdx.x; i < 256 * 32 / 4; i += 256) Wl4[i] = W4[i];
  }
  __syncthreads();

  int t = threadIdx.x;
  int cg = t & 7;                     // 8 col-groups of 4 cols
  int rg = t >> 3;                    // 32 row-groups of 4 rows -> 128 rows/blk
  int c0 = cg * 4;
  long r0 = (long)blockIdx.x * 128 + rg * 4;

  bool rv[4];
#pragma unroll
  for (int i = 0; i < 4; i++) rv[i] = (r0 + i) < (long)N;

  const float* ip = in + r0 * 256;

  float acc[4][4];
#pragma unroll
  for (int i = 0; i < 4; i++)
#pragma unroll
    for (int c = 0; c < 4; c++) acc[i][c] = 0.f;

#pragma unroll 2
  for (int k = 0; k < 256; k += 4) {
    float4 xv[4];
#pragma unroll
    for (int i = 0; i < 4; i++)
      xv[i] = rv[i] ? *(const float4*)(ip + (long)i * 256 + k)
                    : make_float4(0.f, 0.f, 0.f, 0.f);
#pragma unroll
    for (int jj = 0; jj < 4; jj++) {
      const float4 w = *(const float4*)&Wl[(k + jj) * 32 + c0];
#pragma unroll
      for (int i = 0; i < 4; i++) {
        float xs = f4get(xv[i], jj);
        acc[i][0] = fmaf(xs, w.x, acc[i][0]);
        acc[i][1] = fmaf(xs, w.y, acc[i][1]);
        acc[i][2] = fmaf(xs, w.z, acc[i][2]);
        acc[i][3] = fmaf(xs, w.w, acc[i][3]);
      }
    }
  }

#pragma unroll
  for (int i = 0; i < 4; i++) {
    if (!rv[i]) continue;
    float dv = dinv[r0 + i];
    float* op = &out[(r0 + i) * 32 + c0];
    *(float4*)op = make_float4(acc[i][0] * dv, acc[i][1] * dv,
                               acc[i][2] * dv, acc[i][3] * dv);
  }
}

// ---------- tall-skinny fp32 GEMM: out = post(in[NxK] @ W[KxCOLS]) ----------
// ROWS rows x 8 cols per thread; W in LDS. k-loop unroll capped at 2 (R3:
// full unroll hoisted all loads -> 256 VGPR -> scratch spill, 500 MB HBM).
template <int K, int COLS, int ROWS, bool BIAS, bool RELU, bool SCALE, bool DOMAX>
__launch_bounds__(256)
__global__ void k_gemm(const float* __restrict__ in, const float* __restrict__ W,
                       const float* __restrict__ bias, const float* __restrict__ dinv,
                       float* __restrict__ out, int N, unsigned* __restrict__ gmax) {
  constexpr int CG = COLS / 8;        // col-groups of 8
  constexpr int RG = 256 / CG;        // row-groups
  constexpr int RPB = RG * ROWS;      // rows per block
  __shared__ float Wl[K * COLS];
  for (int i = threadIdx.x; i < K * COLS; i += 256) Wl[i] = W[i];
  __syncthreads();

  int cg = threadIdx.x % CG, rg = threadIdx.x / CG;
  int c0 = cg * 8;
  long r0 = (long)blockIdx.x * RPB + rg * ROWS;

  float acc[ROWS][8];
#pragma unroll
  for (int i = 0; i < ROWS; i++)
#pragma unroll
    for (int c = 0; c < 8; c++) acc[i][c] = 0.f;
  bool rv[ROWS];
#pragma unroll
  for (int i = 0; i < ROWS; i++) rv[i] = (r0 + i) < (long)N;

  const float* ip = in + r0 * K;
#pragma unroll 2
  for (int k = 0; k < K; k += 4) {
    float4 xv[ROWS];
#pragma unroll
    for (int i = 0; i < ROWS; i++)
      xv[i] = rv[i] ? *(const float4*)(ip + (long)i * K + k) : make_float4(0.f, 0.f, 0.f, 0.f);
#pragma unroll
    for (int jj = 0; jj < 4; jj++) {
      const float4 wa = *(const float4*)&Wl[(k + jj) * COLS + c0];
      const float4 wb = *(const float4*)&Wl[(k + jj) * COLS + c0 + 4];
#pragma unroll
      for (int i = 0; i < ROWS; i++) {
        float xs = f4get(xv[i], jj);
        acc[i][0] = fmaf(xs, wa.x, acc[i][0]);
        acc[i][1] = fmaf(xs, wa.y, acc[i][1]);
        acc[i][2] = fmaf(xs, wa.z, acc[i][2]);
        acc[i][3] = fmaf(xs, wa.w, acc[i][3]);
        acc[i][4] = fmaf(xs, wb.x, acc[i][4]);
        acc[i][5] = fmaf(xs, wb.y, acc[i][5]);
        acc[i][6] = fmaf(xs, wb.z, acc[i][6]);
        acc[i][7] = fmaf(xs, wb.w, acc[i][7]);
      }
    }
  }

  float bo[8];
  if (BIAS) {
#pragma unroll
    for (int c = 0; c < 8; c++) bo[c] = bias[c0 + c];
  }
  float m = -3.4e38f;
#pragma unroll
  for (int i = 0; i < ROWS; i++) {
    if (!rv[i]) continue;
    float dv = SCALE ? dinv[r0 + i] : 1.f;
    float o[8];
#pragma unroll
    for (int c = 0; c < 8; c++) {
      float v = acc[i][c];
      if (BIAS) v += bo[c];
      if (SCALE) v *= dv;
      if (RELU) v = fmaxf(v, 0.f);
      if (DOMAX) m = fmaxf(m, v);
      o[c] = v;
    }
    float* op = &out[(r0 + i) * COLS + c0];
    *(float4*)(op) = make_float4(o[0], o[1], o[2], o[3]);
    *(float4*)(op + 4) = make_float4(o[4], o[5], o[6], o[7]);
  }
  if constexpr (DOMAX) {
    __shared__ float red[256];
    red[threadIdx.x] = m;
    __syncthreads();
    for (int o = 128; o > 0; o >>= 1) {
      if (threadIdx.x < o) red[threadIdx.x] = fmaxf(red[threadIdx.x], red[threadIdx.x + o]);
      __syncthreads();
    }
    if (threadIdx.x == 0) atomicMax(gmax, fkey(red[0]));
  }
}

// ---------- GCN aggregation (float4 lanes) ----------
template <int FEAT, bool BIAS, bool RELU, bool PSCALE>
__launch_bounds__(256)
__global__ void k_aggv(const float* __restrict__ g, const int* __restrict__ col,
                       const int* __restrict__ rowptr, const int* __restrict__ deg,
                       const float* __restrict__ dinv, const float* __restrict__ bias,
                       float* __restrict__ out, int N) {
  constexpr int LPN = FEAT / 4;       // lanes per node (float4 each)
  constexpr int NPB = 256 / LPN;      // nodes per block
  int nib = threadIdx.x / LPN;
  int c = threadIdx.x % LPN;
  long v = (long)blockIdx.x * NPB + nib;
  if (v >= N) return;

  const float4* g4 = (const float4*)g;
  float4 acc = g4[v * LPN + c];       // self-loop term
  int start = rowptr[v], dg = deg[v];
  int e = 0;
  while (e < dg) {
    int cnt = min(LPN, dg - e);
    int idx = (c < cnt) ? col[start + e + c] : 0;
    int j = 0;
    for (; j + 4 <= cnt; j += 4) {    // 4 independent 16B gathers in flight
      int u0 = __shfl(idx, j + 0, LPN);
      int u1 = __shfl(idx, j + 1, LPN);
      int u2 = __shfl(idx, j + 2, LPN);
      int u3 = __shfl(idx, j + 3, LPN);
      float4 a0 = g4[(long)u0 * LPN + c];
      float4 a1 = g4[(long)u1 * LPN + c];
      float4 a2 = g4[(long)u2 * LPN + c];
      float4 a3 = g4[(long)u3 * LPN + c];
      acc.x += (a0.x + a1.x) + (a2.x + a3.x);
      acc.y += (a0.y + a1.y) + (a2.y + a3.y);
      acc.z += (a0.z + a1.z) + (a2.z + a3.z);
      acc.w += (a0.w + a1.w) + (a2.w + a3.w);
    }
    for (; j < cnt; j++) {
      int u = __shfl(idx, j, LPN);
      float4 a = g4[(long)u * LPN + c];
      acc.x += a.x; acc.y += a.y; acc.z += a.z; acc.w += a.w;
    }
    e += cnt;
  }
  float dv = dinv[v];
  float4 val;
  val.x = acc.x * dv; val.y = acc.y * dv; val.z = acc.z * dv; val.w = acc.w * dv;
  if (BIAS) {
    float4 b = ((const float4*)bias)[c];
    val.x += b.x; val.y += b.y; val.z += b.z; val.w += b.w;
  }
  if (RELU) {
    val.x = fmaxf(val.x, 0.f); val.y = fmaxf(val.y, 0.f);
    val.z = fmaxf(val.z, 0.f); val.w = fmaxf(val.w, 0.f);
  }
  if (PSCALE) {
    val.x *= dv; val.y *= dv; val.z *= dv; val.w *= dv;
  }
  ((float4*)out)[v * LPN + c] = val;
}

// ---------- softmax ----------
__global__ void k_smsum(const float* __restrict__ logit, unsigned* __restrict__ scal, int total) {
  __shared__ float s[256];
  float gmax = funkey(scal[0]);
  float loc = 0.f;
  for (int i = blockIdx.x * 256 + threadIdx.x; i < total; i += gridDim.x * 256)
    loc += expf(logit[i] - gmax);
  s[threadIdx.x] = loc; __syncthreads();
  for (int o = 128; o > 0; o >>= 1) {
    if (threadIdx.x < o) s[threadIdx.x] += s[threadIdx.x + o];
    __syncthreads();
  }
  if (threadIdx.x == 0) atomicAdd((float*)&scal[1], s[0]);
}

__global__ void k_smnorm(float* __restrict__ logit, const unsigned* __restrict__ scal, int total) {
  float gmax = funkey(scal[0]);
  float inv = 1.0f / __uint_as_float(scal[1]);
  int i = blockIdx.x * 256 + threadIdx.x;
  if (i < total) logit[i] = expf(logit[i] - gmax) * inv;
}

// ---------- launch ----------
extern "C" void kernel_launch(void* const* d_in, const int* in_sizes, int n_in,
                              void* d_out, int out_size, void* d_ws, size_t ws_size,
                              hipStream_t stream) {
  const float* x   = (const float*)d_in[0];
  const int*   ei  = (const int*)d_in[1];
  const float* W1  = (const float*)d_in[3];
  const float* b1  = (const float*)d_in[4];
  const float* W2  = (const float*)d_in[5];
  const float* b2  = (const float*)d_in[6];
  const float* Wo1 = (const float*)d_in[7];
  const float* bo1 = (const float*)d_in[8];
  const float* Wo2 = (const float*)d_in[9];
  const float* bo2 = (const float*)d_in[10];

  const int N = in_sizes[0] / 256;   // in_dim = 256
  const int E = in_sizes[1] / 2;
  const int* src = ei;
  const int* dst = ei + E;
  const int NB = (N + BNODES - 1) / BNODES;

  size_t o = 0;
  auto carve = [&](size_t bytes) -> char* {
    char* p = (char*)d_ws + o;
    o += (bytes + 255) & ~(size_t)255;
    return p;
  };
  float* R1     = (float*)carve((size_t)N * 64 * 4);  // g1 | s2 | t
  float* R2     = (float*)carve((size_t)N * 64 * 4);  // epart | p | z2
  int*   col    = (int*)carve((size_t)E * 4);
  int*   deg    = (int*)carve((size_t)N * 4);
  float* dinv   = (float*)carve((size_t)N * 4);
  int*   rowptr = (int*)carve((size_t)N * 4);
  int*   bcnt   = (int*)carve(256 * 4);
  int*   bbase  = (int*)carve(256 * 4);
  int*   bcur   = (int*)carve(256 * 4);
  unsigned* scal = (unsigned*)carve(64);

  unsigned* epart = (unsigned*)R2;  // dead before p is written
  float* g1 = R1;   // N x 32
  float* p  = R2;   // N x 32: dinv .* relu(layer-1 out)
  float* s2 = R1;   // N x 32: aggregated p (g1 dead)
  float* z2 = R2;   // N x 64: relu(s2@W2+b2) (p dead)
  float* t  = R1;   // N x 64: relu(z2@Wo1+bo1) (s2 dead)
  float* logits = (float*)d_out;

  // ---- CSR build ----
  k_binit<<<1, 256, 0, stream>>>(bcnt);
  k_bcount<<<512, 256, 0, stream>>>(dst, bcnt, E, NB);
  k_bscan<<<1, 256, 0, stream>>>(bcnt, bbase, bcur, scal, NB);
  k_bpart<<<(E + PCHUNK - 1) / PCHUNK, 256, 0, stream>>>(src, dst, bcur, epart, E, NB);
  k_fine<<<NB, 256, 0, stream>>>(epart, bbase, bcnt, rowptr, deg, dinv, col, N);

  const int g1G = (N + 127) / 128;  // gemm1: 128 rows per block
  const int gG = (N + 63) / 64;     // 64 rows per block
  const int gA = (N + 31) / 32;     // agg32: 32 nodes per block

  // layer 1: g1 = dinv .* (x @ W1); p = dinv .* relu(b1 + dinv*(g1[v]+sum g1[u]))
  k_gemm1<<<g1G, 256, 0, stream>>>(x, W1, dinv, g1, N);
  k_aggv<32, true, true, true><<<gA, 256, 0, stream>>>(g1, col, rowptr, deg, dinv, b1, p, N);

  // layer 2 (aggregation commuted before W2): s2 = dinv*(p[v]+sum p[u]); z2 = relu(s2@W2+b2)
  k_aggv<32, false, false, false><<<gA, 256, 0, stream>>>(p, col, rowptr, deg, dinv, nullptr, s2, N);
  k_gemm<32, 64, 2, true, true, false, false>
      <<<gG, 256, 0, stream>>>(s2, W2, b2, nullptr, z2, N, nullptr);

  // MLP head
  k_gemm<64, 64, 2, true, true, false, false>
      <<<gG, 256, 0, stream>>>(z2, Wo1, bo1, nullptr, t, N, nullptr);
  k_gemm<64, 64, 2, true, false, false, true>
      <<<gG, 256, 0, stream>>>(t, Wo2, bo2, nullptr, logits, N, scal);

  // softmax over all N*64 logits
  k_smsum<<<1024, 256, 0, stream>>>(logits, scal, out_size);
  k_smnorm<<<(out_size + 255) / 256, 256, 0, stream>>>(logits, scal, out_size);
}

// Round 2
// 553.615 us; speedup vs baseline: 1.0381x; 1.0381x over previous
//
#include <hip/hip_runtime.h>

#define DEVI __device__ __forceinline__

// ---------- helpers ----------
DEVI unsigned fkey(float f) {             // order-preserving float->uint key
  unsigned u = __float_as_uint(f);
  return u ^ ((u >> 31) ? 0xFFFFFFFFu : 0x80000000u);
}
DEVI float funkey(unsigned k) {
  unsigned b = (k & 0x80000000u) ? (k ^ 0x80000000u) : ~k;
  return __uint_as_float(b);
}
DEVI float f4get(const float4& v, int j) {
  return j == 0 ? v.x : j == 1 ? v.y : j == 2 ? v.z : v.w;
}

// ================= CSR build: bucketed counting sort by dst =================
constexpr int BSH = 9;                 // 512 nodes per bucket
constexpr int BNODES = 1 << BSH;
constexpr int PEPT = 16;               // partition: edges per thread
constexpr int PCHUNK = 256 * PEPT;     // 4096 edges per block

__global__ void k_binit(int* __restrict__ bcnt) {
  bcnt[threadIdx.x] = 0;
}

__global__ void k_bcount(const int* __restrict__ dst, int* __restrict__ bcnt,
                         int E, int NB) {
  __shared__ int lh[256];
  lh[threadIdx.x] = 0;
  __syncthreads();
  int stride = gridDim.x * 256;
  for (long i = (long)blockIdx.x * 256 + threadIdx.x; i < E; i += stride)
    atomicAdd(&lh[dst[i] >> BSH], 1);
  __syncthreads();
  if (threadIdx.x < NB && lh[threadIdx.x]) atomicAdd(&bcnt[threadIdx.x], lh[threadIdx.x]);
}

__global__ void k_bscan(const int* __restrict__ bcnt, int* __restrict__ bbase,
                        int* __restrict__ bcur, unsigned* __restrict__ scal, int NB) {
  __shared__ int s[256];
  int t = threadIdx.x;
  int v = (t < NB) ? bcnt[t] : 0;
  s[t] = v;
  __syncthreads();
  for (int o = 1; o < 256; o <<= 1) {
    int add = (t >= o) ? s[t - o] : 0;
    __syncthreads();
    s[t] += add;
    __syncthreads();
  }
  int excl = s[t] - v;
  if (t < NB) { bbase[t] = excl; bcur[t] = excl; }
  if (t == 0) { scal[0] = 0u; scal[1] = 0u; }
}

// pack = (dst&511)<<17 | src  (requires N <= 2^17)
__global__ __launch_bounds__(256)
void k_bpart(const int* __restrict__ src, const int* __restrict__ dst,
             int* __restrict__ bcur, unsigned* __restrict__ epart, int E, int NB) {
  __shared__ int lh[256];
  __shared__ int gbase[256];
  long base = (long)blockIdx.x * PCHUNK;
  lh[threadIdx.x] = 0;
  __syncthreads();
  int ed[PEPT]; int es[PEPT]; unsigned short lpos[PEPT];
#pragma unroll
  for (int j = 0; j < PEPT; j++) {
    long i = base + threadIdx.x + (long)j * 256;   // coalesced
    if (i < E) {
      int d = dst[i];
      es[j] = src[i];
      ed[j] = d;
      lpos[j] = (unsigned short)atomicAdd(&lh[d >> BSH], 1);
    } else {
      ed[j] = -1;
    }
  }
  __syncthreads();
  if (threadIdx.x < NB) {
    int c = lh[threadIdx.x];
    gbase[threadIdx.x] = c ? atomicAdd(&bcur[threadIdx.x], c) : 0;
  }
  __syncthreads();
#pragma unroll
  for (int j = 0; j < PEPT; j++) {
    int d = ed[j];
    if (d >= 0) {
      unsigned p = (unsigned)(gbase[d >> BSH] + (int)lpos[j]);
      epart[p] = ((unsigned)(d & (BNODES - 1)) << 17) | (unsigned)es[j];
    }
  }
}

// one block per bucket: per-node hist + scan -> deg/rowptr/dinv, scatter col
__global__ __launch_bounds__(256)
void k_fine(const unsigned* __restrict__ epart, const int* __restrict__ bbase,
            const int* __restrict__ bcnt, int* __restrict__ rowptr,
            int* __restrict__ deg, float* __restrict__ dinv,
            int* __restrict__ col, int N) {
  __shared__ int lh[BNODES];
  __shared__ int lexcl[BNODES];
  __shared__ int ssc[256];
  int b = blockIdx.x;
  int base = bbase[b], cnt = bcnt[b];
  int nlo = b << BSH;
  int t = threadIdx.x;
  lh[t] = 0; lh[t + 256] = 0;
  __syncthreads();
  for (int i = t; i < cnt; i += 256) {
    unsigned e = epart[base + i];
    atomicAdd(&lh[e >> 17], 1);
  }
  __syncthreads();
  int a0 = lh[2 * t], a1 = lh[2 * t + 1];
  ssc[t] = a0 + a1;
  __syncthreads();
  for (int o = 1; o < 256; o <<= 1) {
    int add = (t >= o) ? ssc[t - o] : 0;
    __syncthreads();
    ssc[t] += add;
    __syncthreads();
  }
  int excl = ssc[t] - (a0 + a1);
  lexcl[2 * t] = excl;
  lexcl[2 * t + 1] = excl + a0;
  __syncthreads();
#pragma unroll
  for (int k = 0; k < 2; k++) {
    int i = t + k * 256;
    int v = nlo + i;
    if (v < N) {
      int dgv = lh[i];
      deg[v] = dgv;
      rowptr[v] = base + lexcl[i];
      dinv[v] = rsqrtf((float)(dgv + 1));
    }
  }
  __syncthreads();
  lh[2 * t] = lexcl[2 * t];
  lh[2 * t + 1] = lexcl[2 * t + 1];
  __syncthreads();
  for (int i = t; i < cnt; i += 256) {
    unsigned e = epart[base + i];
    int p = atomicAdd(&lh[e >> 17], 1);
    col[base + p] = (int)(e & 0x1FFFFu);
  }
}

// ---------- gemm1: x[Nx256] @ W1[256x32], scaled by dinv ----------
// R6 rewrite: R5 post-mortem showed the limiter is wave-level latency hiding
// (3128 waves -> 27% occ, VALUBusy 16%), not LDS issue per se. New structure
// removes W from the vector path entirely: each wave owns ONE 8-col group
// (c0 wave-uniform via readfirstlane) so W rows come in as s_load into SGPRs
// on the scalar pipe. Per k-quad per lane: 1 global float4 (own row) + 32
// v_fma with SGPR W operand. No LDS, no barrier, 6252 waves (24/CU).
__global__ __launch_bounds__(256)
void k_gemm1(const float* __restrict__ in, const float* __restrict__ W,
             const float* __restrict__ dinv, float* __restrict__ out, int N) {
  int t = threadIdx.x;
  int lane = t & 63;
  // wave-uniform col-group base, provably scalar for the compiler
  int c0 = __builtin_amdgcn_readfirstlane((t >> 6) * 8);
  long r = (long)blockIdx.x * 64 + lane;
  bool rv = r < (long)N;

  const float* ip = in + r * 256;
  const float* wp = W + c0;           // uniform pointer -> s_load

  float acc[8];
#pragma unroll
  for (int c = 0; c < 8; c++) acc[c] = 0.f;

#pragma unroll 2
  for (int k = 0; k < 256; k += 4) {
    float4 xv = rv ? *(const float4*)(ip + k) : make_float4(0.f, 0.f, 0.f, 0.f);
#pragma unroll
    for (int jj = 0; jj < 4; jj++) {
      const float* wr = wp + (k + jj) * 32;   // uniform address
      float xs = f4get(xv, jj);
      acc[0] = fmaf(xs, wr[0], acc[0]);
      acc[1] = fmaf(xs, wr[1], acc[1]);
      acc[2] = fmaf(xs, wr[2], acc[2]);
      acc[3] = fmaf(xs, wr[3], acc[3]);
      acc[4] = fmaf(xs, wr[4], acc[4]);
      acc[5] = fmaf(xs, wr[5], acc[5]);
      acc[6] = fmaf(xs, wr[6], acc[6]);
      acc[7] = fmaf(xs, wr[7], acc[7]);
    }
  }

  if (rv) {
    float dv = dinv[r];
    float* op = &out[r * 32 + c0];
    *(float4*)(op) = make_float4(acc[0] * dv, acc[1] * dv, acc[2] * dv, acc[3] * dv);
    *(float4*)(op + 4) = make_float4(acc[4] * dv, acc[5] * dv, acc[6] * dv, acc[7] * dv);
  }
}

// ---------- tall-skinny fp32 GEMM: out = post(in[NxK] @ W[KxCOLS]) ----------
// ROWS rows x 8 cols per thread; W in LDS. k-loop unroll capped at 2 (R3:
// full unroll hoisted all loads -> 256 VGPR -> scratch spill, 500 MB HBM).
template <int K, int COLS, int ROWS, bool BIAS, bool RELU, bool SCALE, bool DOMAX>
__launch_bounds__(256)
__global__ void k_gemm(const float* __restrict__ in, const float* __restrict__ W,
                       const float* __restrict__ bias, const float* __restrict__ dinv,
                       float* __restrict__ out, int N, unsigned* __restrict__ gmax) {
  constexpr int CG = COLS / 8;        // col-groups of 8
  constexpr int RG = 256 / CG;        // row-groups
  constexpr int RPB = RG * ROWS;      // rows per block
  __shared__ float Wl[K * COLS];
  for (int i = threadIdx.x; i < K * COLS; i += 256) Wl[i] = W[i];
  __syncthreads();

  int cg = threadIdx.x % CG, rg = threadIdx.x / CG;
  int c0 = cg * 8;
  long r0 = (long)blockIdx.x * RPB + rg * ROWS;

  float acc[ROWS][8];
#pragma unroll
  for (int i = 0; i < ROWS; i++)
#pragma unroll
    for (int c = 0; c < 8; c++) acc[i][c] = 0.f;
  bool rv[ROWS];
#pragma unroll
  for (int i = 0; i < ROWS; i++) rv[i] = (r0 + i) < (long)N;

  const float* ip = in + r0 * K;
#pragma unroll 2
  for (int k = 0; k < K; k += 4) {
    float4 xv[ROWS];
#pragma unroll
    for (int i = 0; i < ROWS; i++)
      xv[i] = rv[i] ? *(const float4*)(ip + (long)i * K + k) : make_float4(0.f, 0.f, 0.f, 0.f);
#pragma unroll
    for (int jj = 0; jj < 4; jj++) {
      const float4 wa = *(const float4*)&Wl[(k + jj) * COLS + c0];
      const float4 wb = *(const float4*)&Wl[(k + jj) * COLS + c0 + 4];
#pragma unroll
      for (int i = 0; i < ROWS; i++) {
        float xs = f4get(xv[i], jj);
        acc[i][0] = fmaf(xs, wa.x, acc[i][0]);
        acc[i][1] = fmaf(xs, wa.y, acc[i][1]);
        acc[i][2] = fmaf(xs, wa.z, acc[i][2]);
        acc[i][3] = fmaf(xs, wa.w, acc[i][3]);
        acc[i][4] = fmaf(xs, wb.x, acc[i][4]);
        acc[i][5] = fmaf(xs, wb.y, acc[i][5]);
        acc[i][6] = fmaf(xs, wb.z, acc[i][6]);
        acc[i][7] = fmaf(xs, wb.w, acc[i][7]);
      }
    }
  }

  float bo[8];
  if (BIAS) {
#pragma unroll
    for (int c = 0; c < 8; c++) bo[c] = bias[c0 + c];
  }
  float m = -3.4e38f;
#pragma unroll
  for (int i = 0; i < ROWS; i++) {
    if (!rv[i]) continue;
    float dv = SCALE ? dinv[r0 + i] : 1.f;
    float o[8];
#pragma unroll
    for (int c = 0; c < 8; c++) {
      float v = acc[i][c];
      if (BIAS) v += bo[c];
      if (SCALE) v *= dv;
      if (RELU) v = fmaxf(v, 0.f);
      if (DOMAX) m = fmaxf(m, v);
      o[c] = v;
    }
    float* op = &out[(r0 + i) * COLS + c0];
    *(float4*)(op) = make_float4(o[0], o[1], o[2], o[3]);
    *(float4*)(op + 4) = make_float4(o[4], o[5], o[6], o[7]);
  }
  if constexpr (DOMAX) {
    __shared__ float red[256];
    red[threadIdx.x] = m;
    __syncthreads();
    for (int o = 128; o > 0; o >>= 1) {
      if (threadIdx.x < o) red[threadIdx.x] = fmaxf(red[threadIdx.x], red[threadIdx.x + o]);
      __syncthreads();
    }
    if (threadIdx.x == 0) atomicMax(gmax, fkey(red[0]));
  }
}

// ---------- GCN aggregation (float4 lanes) ----------
template <int FEAT, bool BIAS, bool RELU, bool PSCALE>
__launch_bounds__(256)
__global__ void k_aggv(const float* __restrict__ g, const int* __restrict__ col,
                       const int* __restrict__ rowptr, const int* __restrict__ deg,
                       const float* __restrict__ dinv, const float* __restrict__ bias,
                       float* __restrict__ out, int N) {
  constexpr int LPN = FEAT / 4;       // lanes per node (float4 each)
  constexpr int NPB = 256 / LPN;      // nodes per block
  int nib = threadIdx.x / LPN;
  int c = threadIdx.x % LPN;
  long v = (long)blockIdx.x * NPB + nib;
  if (v >= N) return;

  const float4* g4 = (const float4*)g;
  float4 acc = g4[v * LPN + c];       // self-loop term
  int start = rowptr[v], dg = deg[v];
  int e = 0;
  while (e < dg) {
    int cnt = min(LPN, dg - e);
    int idx = (c < cnt) ? col[start + e + c] : 0;
    int j = 0;
    for (; j + 4 <= cnt; j += 4) {    // 4 independent 16B gathers in flight
      int u0 = __shfl(idx, j + 0, LPN);
      int u1 = __shfl(idx, j + 1, LPN);
      int u2 = __shfl(idx, j + 2, LPN);
      int u3 = __shfl(idx, j + 3, LPN);
      float4 a0 = g4[(long)u0 * LPN + c];
      float4 a1 = g4[(long)u1 * LPN + c];
      float4 a2 = g4[(long)u2 * LPN + c];
      float4 a3 = g4[(long)u3 * LPN + c];
      acc.x += (a0.x + a1.x) + (a2.x + a3.x);
      acc.y += (a0.y + a1.y) + (a2.y + a3.y);
      acc.z += (a0.z + a1.z) + (a2.z + a3.z);
      acc.w += (a0.w + a1.w) + (a2.w + a3.w);
    }
    for (; j < cnt; j++) {
      int u = __shfl(idx, j, LPN);
      float4 a = g4[(long)u * LPN + c];
      acc.x += a.x; acc.y += a.y; acc.z += a.z; acc.w += a.w;
    }
    e += cnt;
  }
  float dv = dinv[v];
  float4 val;
  val.x = acc.x * dv; val.y = acc.y * dv; val.z = acc.z * dv; val.w = acc.w * dv;
  if (BIAS) {
    float4 b = ((const float4*)bias)[c];
    val.x += b.x; val.y += b.y; val.z += b.z; val.w += b.w;
  }
  if (RELU) {
    val.x = fmaxf(val.x, 0.f); val.y = fmaxf(val.y, 0.f);
    val.z = fmaxf(val.z, 0.f); val.w = fmaxf(val.w, 0.f);
  }
  if (PSCALE) {
    val.x *= dv; val.y *= dv; val.z *= dv; val.w *= dv;
  }
  ((float4*)out)[v * LPN + c] = val;
}

// ---------- softmax ----------
__global__ void k_smsum(const float* __restrict__ logit, unsigned* __restrict__ scal, int total) {
  __shared__ float s[256];
  float gmax = funkey(scal[0]);
  float loc = 0.f;
  for (int i = blockIdx.x * 256 + threadIdx.x; i < total; i += gridDim.x * 256)
    loc += expf(logit[i] - gmax);
  s[threadIdx.x] = loc; __syncthreads();
  for (int o = 128; o > 0; o >>= 1) {
    if (threadIdx.x < o) s[threadIdx.x] += s[threadIdx.x + o];
    __syncthreads();
  }
  if (threadIdx.x == 0) atomicAdd((float*)&scal[1], s[0]);
}

__global__ void k_smnorm(float* __restrict__ logit, const unsigned* __restrict__ scal, int total) {
  float gmax = funkey(scal[0]);
  float inv = 1.0f / __uint_as_float(scal[1]);
  int i = blockIdx.x * 256 + threadIdx.x;
  if (i < total) logit[i] = expf(logit[i] - gmax) * inv;
}

// ---------- launch ----------
extern "C" void kernel_launch(void* const* d_in, const int* in_sizes, int n_in,
                              void* d_out, int out_size, void* d_ws, size_t ws_size,
                              hipStream_t stream) {
  const float* x   = (const float*)d_in[0];
  const int*   ei  = (const int*)d_in[1];
  const float* W1  = (const float*)d_in[3];
  const float* b1  = (const float*)d_in[4];
  const float* W2  = (const float*)d_in[5];
  const float* b2  = (const float*)d_in[6];
  const float* Wo1 = (const float*)d_in[7];
  const float* bo1 = (const float*)d_in[8];
  const float* Wo2 = (const float*)d_in[9];
  const float* bo2 = (const float*)d_in[10];

  const int N = in_sizes[0] / 256;   // in_dim = 256
  const int E = in_sizes[1] / 2;
  const int* src = ei;
  const int* dst = ei + E;
  const int NB = (N + BNODES - 1) / BNODES;

  size_t o = 0;
  auto carve = [&](size_t bytes) -> char* {
    char* p = (char*)d_ws + o;
    o += (bytes + 255) & ~(size_t)255;
    return p;
  };
  float* R1     = (float*)carve((size_t)N * 64 * 4);  // g1 | s2 | t
  float* R2     = (float*)carve((size_t)N * 64 * 4);  // epart | p | z2
  int*   col    = (int*)carve((size_t)E * 4);
  int*   deg    = (int*)carve((size_t)N * 4);
  float* dinv   = (float*)carve((size_t)N * 4);
  int*   rowptr = (int*)carve((size_t)N * 4);
  int*   bcnt   = (int*)carve(256 * 4);
  int*   bbase  = (int*)carve(256 * 4);
  int*   bcur   = (int*)carve(256 * 4);
  unsigned* scal = (unsigned*)carve(64);

  unsigned* epart = (unsigned*)R2;  // dead before p is written
  float* g1 = R1;   // N x 32
  float* p  = R2;   // N x 32: dinv .* relu(layer-1 out)
  float* s2 = R1;   // N x 32: aggregated p (g1 dead)
  float* z2 = R2;   // N x 64: relu(s2@W2+b2) (p dead)
  float* t  = R1;   // N x 64: relu(z2@Wo1+bo1) (s2 dead)
  float* logits = (float*)d_out;

  // ---- CSR build ----
  k_binit<<<1, 256, 0, stream>>>(bcnt);
  k_bcount<<<512, 256, 0, stream>>>(dst, bcnt, E, NB);
  k_bscan<<<1, 256, 0, stream>>>(bcnt, bbase, bcur, scal, NB);
  k_bpart<<<(E + PCHUNK - 1) / PCHUNK, 256, 0, stream>>>(src, dst, bcur, epart, E, NB);
  k_fine<<<NB, 256, 0, stream>>>(epart, bbase, bcnt, rowptr, deg, dinv, col, N);

  const int gG = (N + 63) / 64;     // 64 rows per block
  const int gA = (N + 31) / 32;     // agg32: 32 nodes per block

  // layer 1: g1 = dinv .* (x @ W1); p = dinv .* relu(b1 + dinv*(g1[v]+sum g1[u]))
  k_gemm1<<<gG, 256, 0, stream>>>(x, W1, dinv, g1, N);
  k_aggv<32, true, true, true><<<gA, 256, 0, stream>>>(g1, col, rowptr, deg, dinv, b1, p, N);

  // layer 2 (aggregation commuted before W2): s2 = dinv*(p[v]+sum p[u]); z2 = relu(s2@W2+b2)
  k_aggv<32, false, false, false><<<gA, 256, 0, stream>>>(p, col, rowptr, deg, dinv, nullptr, s2, N);
  k_gemm<32, 64, 2, true, true, false, false>
      <<<gG, 256, 0, stream>>>(s2, W2, b2, nullptr, z2, N, nullptr);

  // MLP head
  k_gemm<64, 64, 2, true, true, false, false>
      <<<gG, 256, 0, stream>>>(z2, Wo1, bo1, nullptr, t, N, nullptr);
  k_gemm<64, 64, 2, true, false, false, true>
      <<<gG, 256, 0, stream>>>(t, Wo2, bo2, nullptr, logits, N, scal);

  // softmax over all N*64 logits
  k_smsum<<<1024, 256, 0, stream>>>(logits, scal, out_size);
  k_smnorm<<<(out_size + 255) / 256, 256, 0, stream>>>(logits, scal, out_size);
}

// Round 3
// 517.628 us; speedup vs baseline: 1.1103x; 1.0695x over previous
//
#include <hip/hip_runtime.h>

#define DEVI __device__ __forceinline__

// ---------- helpers ----------
DEVI unsigned fkey(float f) {             // order-preserving float->uint key
  unsigned u = __float_as_uint(f);
  return u ^ ((u >> 31) ? 0xFFFFFFFFu : 0x80000000u);
}
DEVI float funkey(unsigned k) {
  unsigned b = (k & 0x80000000u) ? (k ^ 0x80000000u) : ~k;
  return __uint_as_float(b);
}
DEVI float f4get(const float4& v, int j) {
  return j == 0 ? v.x : j == 1 ? v.y : j == 2 ? v.z : v.w;
}

// ================= CSR build: bucketed counting sort by dst =================
constexpr int BSH = 9;                 // 512 nodes per bucket
constexpr int BNODES = 1 << BSH;
constexpr int PEPT = 16;               // partition: edges per thread
constexpr int PCHUNK = 256 * PEPT;     // 4096 edges per block

__global__ void k_binit(int* __restrict__ bcnt) {
  bcnt[threadIdx.x] = 0;
}

__global__ void k_bcount(const int* __restrict__ dst, int* __restrict__ bcnt,
                         int E, int NB) {
  __shared__ int lh[256];
  lh[threadIdx.x] = 0;
  __syncthreads();
  int stride = gridDim.x * 256;
  for (long i = (long)blockIdx.x * 256 + threadIdx.x; i < E; i += stride)
    atomicAdd(&lh[dst[i] >> BSH], 1);
  __syncthreads();
  if (threadIdx.x < NB && lh[threadIdx.x]) atomicAdd(&bcnt[threadIdx.x], lh[threadIdx.x]);
}

__global__ void k_bscan(const int* __restrict__ bcnt, int* __restrict__ bbase,
                        int* __restrict__ bcur, unsigned* __restrict__ scal, int NB) {
  __shared__ int s[256];
  int t = threadIdx.x;
  int v = (t < NB) ? bcnt[t] : 0;
  s[t] = v;
  __syncthreads();
  for (int o = 1; o < 256; o <<= 1) {
    int add = (t >= o) ? s[t - o] : 0;
    __syncthreads();
    s[t] += add;
    __syncthreads();
  }
  int excl = s[t] - v;
  if (t < NB) { bbase[t] = excl; bcur[t] = excl; }
  if (t == 0) { scal[0] = 0u; scal[1] = 0u; }
}

// pack = (dst&511)<<17 | src  (requires N <= 2^17)
__global__ __launch_bounds__(256)
void k_bpart(const int* __restrict__ src, const int* __restrict__ dst,
             int* __restrict__ bcur, unsigned* __restrict__ epart, int E, int NB) {
  __shared__ int lh[256];
  __shared__ int gbase[256];
  long base = (long)blockIdx.x * PCHUNK;
  lh[threadIdx.x] = 0;
  __syncthreads();
  int ed[PEPT]; int es[PEPT]; unsigned short lpos[PEPT];
#pragma unroll
  for (int j = 0; j < PEPT; j++) {
    long i = base + threadIdx.x + (long)j * 256;   // coalesced
    if (i < E) {
      int d = dst[i];
      es[j] = src[i];
      ed[j] = d;
      lpos[j] = (unsigned short)atomicAdd(&lh[d >> BSH], 1);
    } else {
      ed[j] = -1;
    }
  }
  __syncthreads();
  if (threadIdx.x < NB) {
    int c = lh[threadIdx.x];
    gbase[threadIdx.x] = c ? atomicAdd(&bcur[threadIdx.x], c) : 0;
  }
  __syncthreads();
#pragma unroll
  for (int j = 0; j < PEPT; j++) {
    int d = ed[j];
    if (d >= 0) {
      unsigned p = (unsigned)(gbase[d >> BSH] + (int)lpos[j]);
      epart[p] = ((unsigned)(d & (BNODES - 1)) << 17) | (unsigned)es[j];
    }
  }
}

// one block per bucket: per-node hist + scan -> deg/rowptr/dinv, scatter col
__global__ __launch_bounds__(256)
void k_fine(const unsigned* __restrict__ epart, const int* __restrict__ bbase,
            const int* __restrict__ bcnt, int* __restrict__ rowptr,
            int* __restrict__ deg, float* __restrict__ dinv,
            int* __restrict__ col, int N) {
  __shared__ int lh[BNODES];
  __shared__ int lexcl[BNODES];
  __shared__ int ssc[256];
  int b = blockIdx.x;
  int base = bbase[b], cnt = bcnt[b];
  int nlo = b << BSH;
  int t = threadIdx.x;
  lh[t] = 0; lh[t + 256] = 0;
  __syncthreads();
  for (int i = t; i < cnt; i += 256) {
    unsigned e = epart[base + i];
    atomicAdd(&lh[e >> 17], 1);
  }
  __syncthreads();
  int a0 = lh[2 * t], a1 = lh[2 * t + 1];
  ssc[t] = a0 + a1;
  __syncthreads();
  for (int o = 1; o < 256; o <<= 1) {
    int add = (t >= o) ? ssc[t - o] : 0;
    __syncthreads();
    ssc[t] += add;
    __syncthreads();
  }
  int excl = ssc[t] - (a0 + a1);
  lexcl[2 * t] = excl;
  lexcl[2 * t + 1] = excl + a0;
  __syncthreads();
#pragma unroll
  for (int k = 0; k < 2; k++) {
    int i = t + k * 256;
    int v = nlo + i;
    if (v < N) {
      int dgv = lh[i];
      deg[v] = dgv;
      rowptr[v] = base + lexcl[i];
      dinv[v] = rsqrtf((float)(dgv + 1));
    }
  }
  __syncthreads();
  lh[2 * t] = lexcl[2 * t];
  lh[2 * t + 1] = lexcl[2 * t + 1];
  __syncthreads();
  for (int i = t; i < cnt; i += 256) {
    unsigned e = epart[base + i];
    int p = atomicAdd(&lh[e >> 17], 1);
    col[base + p] = (int)(e & 0x1FFFFu);
  }
}

// ---------- gemm1: x[Nx256] @ W1[256x32], scaled by dinv ----------
// R7 rewrite. R4/R5/R6 post-mortem: all shared per-lane-row x loads (16B per
// lane at 1KB stride) -> 4KB active lines per wave, 80-128KB per CU vs 32KB
// L1 -> every x load was an L2/L3-latency miss on the critical path; time
// fitted t ~= 56us + 212k/waves (asymptote = that latency). Fix: cooperative
// coalesced staging of x into LDS (double-buffered, prefetch overlapped),
// compute fed from LDS. 256 thr, 128 rows/block (782 blocks = 3.05/CU),
// C=8 cols x R=2 rows per thread, K chunked x16 (Kc=16). LDS 48KB ->
// 3 blocks/CU. x slots XOR-swizzled by (row>>1)&3 so compute reads are
// ~2-way (free); W reads are 4-lane broadcast at bank starts {0,8,16,24}.
__global__ __launch_bounds__(256)
void k_gemm1(const float* __restrict__ in, const float* __restrict__ W,
             const float* __restrict__ dinv, float* __restrict__ out, int N) {
  __shared__ float Wl[256 * 32];          // 32 KB
  __shared__ float xb[2][128 * 16];       // 2 x 8 KB
  const int t = threadIdx.x;

  // ---- stage W (once), coalesced float4 ----
  {
    const float4* W4 = (const float4*)W;
    float4* Wl4 = (float4*)Wl;
#pragma unroll
    for (int i = 0; i < 8; i++) Wl4[t + i * 256] = W4[t + i * 256];
  }

  // staging ids: 2 threads per row, 2 float4 (= 2 swizzled quads) each
  const int srow = t >> 1;                // 0..127
  const int part = t & 1;
  const int sk = (srow >> 1) & 3;         // swizzle key for this row
  long grow = (long)blockIdx.x * 128 + srow;
  const float* gsrc = in + (grow < (long)N ? grow : (long)(N - 1)) * 256 + part * 8;
  const int q0 = part * 2, q1 = part * 2 + 1;
  const int ws0 = srow * 16 + ((q0 ^ sk) << 2);
  const int ws1 = srow * 16 + ((q1 ^ sk) << 2);

  // compute ids: 4 col-groups x 64 row-groups, rows rg and rg+64
  const int cg = t & 3;
  const int rg = t >> 2;                  // 0..63
  const int c0 = cg * 8;
  const int rk = (rg >> 1) & 3;           // (rg+64)>>1 &3 == rk as well? no:
  // (rg+64)>>1 = rg>>1 + 32 -> &3 unchanged (32%4==0) -> same key. OK.

  // ---- stage chunk 0 ----
  {
    float4 a = *(const float4*)(gsrc + 0);
    float4 b = *(const float4*)(gsrc + 4);
    *(float4*)&xb[0][ws0] = a;
    *(float4*)&xb[0][ws1] = b;
  }
  __syncthreads();

  float acc[2][8];
#pragma unroll
  for (int i = 0; i < 2; i++)
#pragma unroll
    for (int c = 0; c < 8; c++) acc[i][c] = 0.f;

  for (int ch = 0; ch < 16; ch++) {
    float4 na, nb;
    if (ch < 15) {                        // prefetch next chunk into regs
      na = *(const float4*)(gsrc + (ch + 1) * 16 + 0);
      nb = *(const float4*)(gsrc + (ch + 1) * 16 + 4);
    }
    const float* xc = xb[ch & 1];
#pragma unroll
    for (int q = 0; q < 4; q++) {
      float4 xv0 = *(const float4*)&xc[rg * 16 + ((q ^ rk) << 2)];
      float4 xv1 = *(const float4*)&xc[(rg + 64) * 16 + ((q ^ rk) << 2)];
#pragma unroll
      for (int jj = 0; jj < 4; jj++) {
        const float* wr = &Wl[(ch * 16 + q * 4 + jj) * 32 + c0];
        float4 wa = *(const float4*)(wr);
        float4 wb = *(const float4*)(wr + 4);
        float x0 = f4get(xv0, jj);
        float x1 = f4get(xv1, jj);
        acc[0][0] = fmaf(x0, wa.x, acc[0][0]);
        acc[0][1] = fmaf(x0, wa.y, acc[0][1]);
        acc[0][2] = fmaf(x0, wa.z, acc[0][2]);
        acc[0][3] = fmaf(x0, wa.w, acc[0][3]);
        acc[0][4] = fmaf(x0, wb.x, acc[0][4]);
        acc[0][5] = fmaf(x0, wb.y, acc[0][5]);
        acc[0][6] = fmaf(x0, wb.z, acc[0][6]);
        acc[0][7] = fmaf(x0, wb.w, acc[0][7]);
        acc[1][0] = fmaf(x1, wa.x, acc[1][0]);
        acc[1][1] = fmaf(x1, wa.y, acc[1][1]);
        acc[1][2] = fmaf(x1, wa.z, acc[1][2]);
        acc[1][3] = fmaf(x1, wa.w, acc[1][3]);
        acc[1][4] = fmaf(x1, wb.x, acc[1][4]);
        acc[1][5] = fmaf(x1, wb.y, acc[1][5]);
        acc[1][6] = fmaf(x1, wb.z, acc[1][6]);
        acc[1][7] = fmaf(x1, wb.w, acc[1][7]);
      }
    }
    if (ch < 15) {
      __syncthreads();                    // readers of target buffer done
      float* xn = xb[(ch + 1) & 1];
      *(float4*)&xn[ws0] = na;
      *(float4*)&xn[ws1] = nb;
      __syncthreads();                    // writes visible before compute
    }
  }

  // ---- epilogue: scale by dinv, store ----
#pragma unroll
  for (int i = 0; i < 2; i++) {
    long r = (long)blockIdx.x * 128 + rg + i * 64;
    if (r < (long)N) {
      float dv = dinv[r];
      float* op = &out[r * 32 + c0];
      *(float4*)(op) = make_float4(acc[i][0] * dv, acc[i][1] * dv,
                                   acc[i][2] * dv, acc[i][3] * dv);
      *(float4*)(op + 4) = make_float4(acc[i][4] * dv, acc[i][5] * dv,
                                       acc[i][6] * dv, acc[i][7] * dv);
    }
  }
}

// ---------- tall-skinny fp32 GEMM: out = post(in[NxK] @ W[KxCOLS]) ----------
// ROWS rows x 8 cols per thread; W in LDS. k-loop unroll capped at 2 (R3:
// full unroll hoisted all loads -> 256 VGPR -> scratch spill, 500 MB HBM).
template <int K, int COLS, int ROWS, bool BIAS, bool RELU, bool SCALE, bool DOMAX>
__launch_bounds__(256)
__global__ void k_gemm(const float* __restrict__ in, const float* __restrict__ W,
                       const float* __restrict__ bias, const float* __restrict__ dinv,
                       float* __restrict__ out, int N, unsigned* __restrict__ gmax) {
  constexpr int CG = COLS / 8;        // col-groups of 8
  constexpr int RG = 256 / CG;        // row-groups
  constexpr int RPB = RG * ROWS;      // rows per block
  __shared__ float Wl[K * COLS];
  for (int i = threadIdx.x; i < K * COLS; i += 256) Wl[i] = W[i];
  __syncthreads();

  int cg = threadIdx.x % CG, rg = threadIdx.x / CG;
  int c0 = cg * 8;
  long r0 = (long)blockIdx.x * RPB + rg * ROWS;

  float acc[ROWS][8];
#pragma unroll
  for (int i = 0; i < ROWS; i++)
#pragma unroll
    for (int c = 0; c < 8; c++) acc[i][c] = 0.f;
  bool rv[ROWS];
#pragma unroll
  for (int i = 0; i < ROWS; i++) rv[i] = (r0 + i) < (long)N;

  const float* ip = in + r0 * K;
#pragma unroll 2
  for (int k = 0; k < K; k += 4) {
    float4 xv[ROWS];
#pragma unroll
    for (int i = 0; i < ROWS; i++)
      xv[i] = rv[i] ? *(const float4*)(ip + (long)i * K + k) : make_float4(0.f, 0.f, 0.f, 0.f);
#pragma unroll
    for (int jj = 0; jj < 4; jj++) {
      const float4 wa = *(const float4*)&Wl[(k + jj) * COLS + c0];
      const float4 wb = *(const float4*)&Wl[(k + jj) * COLS + c0 + 4];
#pragma unroll
      for (int i = 0; i < ROWS; i++) {
        float xs = f4get(xv[i], jj);
        acc[i][0] = fmaf(xs, wa.x, acc[i][0]);
        acc[i][1] = fmaf(xs, wa.y, acc[i][1]);
        acc[i][2] = fmaf(xs, wa.z, acc[i][2]);
        acc[i][3] = fmaf(xs, wa.w, acc[i][3]);
        acc[i][4] = fmaf(xs, wb.x, acc[i][4]);
        acc[i][5] = fmaf(xs, wb.y, acc[i][5]);
        acc[i][6] = fmaf(xs, wb.z, acc[i][6]);
        acc[i][7] = fmaf(xs, wb.w, acc[i][7]);
      }
    }
  }

  float bo[8];
  if (BIAS) {
#pragma unroll
    for (int c = 0; c < 8; c++) bo[c] = bias[c0 + c];
  }
  float m = -3.4e38f;
#pragma unroll
  for (int i = 0; i < ROWS; i++) {
    if (!rv[i]) continue;
    float dv = SCALE ? dinv[r0 + i] : 1.f;
    float o[8];
#pragma unroll
    for (int c = 0; c < 8; c++) {
      float v = acc[i][c];
      if (BIAS) v += bo[c];
      if (SCALE) v *= dv;
      if (RELU) v = fmaxf(v, 0.f);
      if (DOMAX) m = fmaxf(m, v);
      o[c] = v;
    }
    float* op = &out[(r0 + i) * COLS + c0];
    *(float4*)(op) = make_float4(o[0], o[1], o[2], o[3]);
    *(float4*)(op + 4) = make_float4(o[4], o[5], o[6], o[7]);
  }
  if constexpr (DOMAX) {
    __shared__ float red[256];
    red[threadIdx.x] = m;
    __syncthreads();
    for (int o = 128; o > 0; o >>= 1) {
      if (threadIdx.x < o) red[threadIdx.x] = fmaxf(red[threadIdx.x], red[threadIdx.x + o]);
      __syncthreads();
    }
    if (threadIdx.x == 0) atomicMax(gmax, fkey(red[0]));
  }
}

// ---------- GCN aggregation (float4 lanes) ----------
template <int FEAT, bool BIAS, bool RELU, bool PSCALE>
__launch_bounds__(256)
__global__ void k_aggv(const float* __restrict__ g, const int* __restrict__ col,
                       const int* __restrict__ rowptr, const int* __restrict__ deg,
                       const float* __restrict__ dinv, const float* __restrict__ bias,
                       float* __restrict__ out, int N) {
  constexpr int LPN = FEAT / 4;       // lanes per node (float4 each)
  constexpr int NPB = 256 / LPN;      // nodes per block
  int nib = threadIdx.x / LPN;
  int c = threadIdx.x % LPN;
  long v = (long)blockIdx.x * NPB + nib;
  if (v >= N) return;

  const float4* g4 = (const float4*)g;
  float4 acc = g4[v * LPN + c];       // self-loop term
  int start = rowptr[v], dg = deg[v];
  int e = 0;
  while (e < dg) {
    int cnt = min(LPN, dg - e);
    int idx = (c < cnt) ? col[start + e + c] : 0;
    int j = 0;
    for (; j + 4 <= cnt; j += 4) {    // 4 independent 16B gathers in flight
      int u0 = __shfl(idx, j + 0, LPN);
      int u1 = __shfl(idx, j + 1, LPN);
      int u2 = __shfl(idx, j + 2, LPN);
      int u3 = __shfl(idx, j + 3, LPN);
      float4 a0 = g4[(long)u0 * LPN + c];
      float4 a1 = g4[(long)u1 * LPN + c];
      float4 a2 = g4[(long)u2 * LPN + c];
      float4 a3 = g4[(long)u3 * LPN + c];
      acc.x += (a0.x + a1.x) + (a2.x + a3.x);
      acc.y += (a0.y + a1.y) + (a2.y + a3.y);
      acc.z += (a0.z + a1.z) + (a2.z + a3.z);
      acc.w += (a0.w + a1.w) + (a2.w + a3.w);
    }
    for (; j < cnt; j++) {
      int u = __shfl(idx, j, LPN);
      float4 a = g4[(long)u * LPN + c];
      acc.x += a.x; acc.y += a.y; acc.z += a.z; acc.w += a.w;
    }
    e += cnt;
  }
  float dv = dinv[v];
  float4 val;
  val.x = acc.x * dv; val.y = acc.y * dv; val.z = acc.z * dv; val.w = acc.w * dv;
  if (BIAS) {
    float4 b = ((const float4*)bias)[c];
    val.x += b.x; val.y += b.y; val.z += b.z; val.w += b.w;
  }
  if (RELU) {
    val.x = fmaxf(val.x, 0.f); val.y = fmaxf(val.y, 0.f);
    val.z = fmaxf(val.z, 0.f); val.w = fmaxf(val.w, 0.f);
  }
  if (PSCALE) {
    val.x *= dv; val.y *= dv; val.z *= dv; val.w *= dv;
  }
  ((float4*)out)[v * LPN + c] = val;
}

// ---------- softmax ----------
__global__ void k_smsum(const float* __restrict__ logit, unsigned* __restrict__ scal, int total) {
  __shared__ float s[256];
  float gmax = funkey(scal[0]);
  float loc = 0.f;
  for (int i = blockIdx.x * 256 + threadIdx.x; i < total; i += gridDim.x * 256)
    loc += expf(logit[i] - gmax);
  s[threadIdx.x] = loc; __syncthreads();
  for (int o = 128; o > 0; o >>= 1) {
    if (threadIdx.x < o) s[threadIdx.x] += s[threadIdx.x + o];
    __syncthreads();
  }
  if (threadIdx.x == 0) atomicAdd((float*)&scal[1], s[0]);
}

__global__ void k_smnorm(float* __restrict__ logit, const unsigned* __restrict__ scal, int total) {
  float gmax = funkey(scal[0]);
  float inv = 1.0f / __uint_as_float(scal[1]);
  int i = blockIdx.x * 256 + threadIdx.x;
  if (i < total) logit[i] = expf(logit[i] - gmax) * inv;
}

// ---------- launch ----------
extern "C" void kernel_launch(void* const* d_in, const int* in_sizes, int n_in,
                              void* d_out, int out_size, void* d_ws, size_t ws_size,
                              hipStream_t stream) {
  const float* x   = (const float*)d_in[0];
  const int*   ei  = (const int*)d_in[1];
  const float* W1  = (const float*)d_in[3];
  const float* b1  = (const float*)d_in[4];
  const float* W2  = (const float*)d_in[5];
  const float* b2  = (const float*)d_in[6];
  const float* Wo1 = (const float*)d_in[7];
  const float* bo1 = (const float*)d_in[8];
  const float* Wo2 = (const float*)d_in[9];
  const float* bo2 = (const float*)d_in[10];

  const int N = in_sizes[0] / 256;   // in_dim = 256
  const int E = in_sizes[1] / 2;
  const int* src = ei;
  const int* dst = ei + E;
  const int NB = (N + BNODES - 1) / BNODES;

  size_t o = 0;
  auto carve = [&](size_t bytes) -> char* {
    char* p = (char*)d_ws + o;
    o += (bytes + 255) & ~(size_t)255;
    return p;
  };
  float* R1     = (float*)carve((size_t)N * 64 * 4);  // g1 | s2 | t
  float* R2     = (float*)carve((size_t)N * 64 * 4);  // epart | p | z2
  int*   col    = (int*)carve((size_t)E * 4);
  int*   deg    = (int*)carve((size_t)N * 4);
  float* dinv   = (float*)carve((size_t)N * 4);
  int*   rowptr = (int*)carve((size_t)N * 4);
  int*   bcnt   = (int*)carve(256 * 4);
  int*   bbase  = (int*)carve(256 * 4);
  int*   bcur   = (int*)carve(256 * 4);
  unsigned* scal = (unsigned*)carve(64);

  unsigned* epart = (unsigned*)R2;  // dead before p is written
  float* g1 = R1;   // N x 32
  float* p  = R2;   // N x 32: dinv .* relu(layer-1 out)
  float* s2 = R1;   // N x 32: aggregated p (g1 dead)
  float* z2 = R2;   // N x 64: relu(s2@W2+b2) (p dead)
  float* t  = R1;   // N x 64: relu(z2@Wo1+bo1) (s2 dead)
  float* logits = (float*)d_out;

  // ---- CSR build ----
  k_binit<<<1, 256, 0, stream>>>(bcnt);
  k_bcount<<<512, 256, 0, stream>>>(dst, bcnt, E, NB);
  k_bscan<<<1, 256, 0, stream>>>(bcnt, bbase, bcur, scal, NB);
  k_bpart<<<(E + PCHUNK - 1) / PCHUNK, 256, 0, stream>>>(src, dst, bcur, epart, E, NB);
  k_fine<<<NB, 256, 0, stream>>>(epart, bbase, bcnt, rowptr, deg, dinv, col, N);

  const int g1G = (N + 127) / 128;  // gemm1: 128 rows per block
  const int gG = (N + 63) / 64;     // 64 rows per block
  const int gA = (N + 31) / 32;     // agg32: 32 nodes per block

  // layer 1: g1 = dinv .* (x @ W1); p = dinv .* relu(b1 + dinv*(g1[v]+sum g1[u]))
  k_gemm1<<<g1G, 256, 0, stream>>>(x, W1, dinv, g1, N);
  k_aggv<32, true, true, true><<<gA, 256, 0, stream>>>(g1, col, rowptr, deg, dinv, b1, p, N);

  // layer 2 (aggregation commuted before W2): s2 = dinv*(p[v]+sum p[u]); z2 = relu(s2@W2+b2)
  k_aggv<32, false, false, false><<<gA, 256, 0, stream>>>(p, col, rowptr, deg, dinv, nullptr, s2, N);
  k_gemm<32, 64, 2, true, true, false, false>
      <<<gG, 256, 0, stream>>>(s2, W2, b2, nullptr, z2, N, nullptr);

  // MLP head
  k_gemm<64, 64, 2, true, true, false, false>
      <<<gG, 256, 0, stream>>>(z2, Wo1, bo1, nullptr, t, N, nullptr);
  k_gemm<64, 64, 2, true, false, false, true>
      <<<gG, 256, 0, stream>>>(t, Wo2, bo2, nullptr, logits, N, scal);

  // softmax over all N*64 logits
  k_smsum<<<1024, 256, 0, stream>>>(logits, scal, out_size);
  k_smnorm<<<(out_size + 255) / 256, 256, 0, stream>>>(logits, scal, out_size);
}

// Round 4
// 495.946 us; speedup vs baseline: 1.1588x; 1.0437x over previous
//
#include <hip/hip_runtime.h>

#define DEVI __device__ __forceinline__

// ---------- helpers ----------
DEVI unsigned fkey(float f) {             // order-preserving float->uint key
  unsigned u = __float_as_uint(f);
  return u ^ ((u >> 31) ? 0xFFFFFFFFu : 0x80000000u);
}
DEVI float funkey(unsigned k) {
  unsigned b = (k & 0x80000000u) ? (k ^ 0x80000000u) : ~k;
  return __uint_as_float(b);
}
DEVI float f4get(const float4& v, int j) {
  return j == 0 ? v.x : j == 1 ? v.y : j == 2 ? v.z : v.w;
}

// ================= CSR build: bucketed counting sort by dst =================
constexpr int BSH = 9;                 // 512 nodes per bucket
constexpr int BNODES = 1 << BSH;
constexpr int PEPT = 16;               // partition: edges per thread
constexpr int PCHUNK = 256 * PEPT;     // 4096 edges per block

__global__ void k_binit(int* __restrict__ bcnt) {
  bcnt[threadIdx.x] = 0;
}

__global__ void k_bcount(const int* __restrict__ dst, int* __restrict__ bcnt,
                         int E, int NB) {
  __shared__ int lh[256];
  lh[threadIdx.x] = 0;
  __syncthreads();
  int stride = gridDim.x * 256;
  for (long i = (long)blockIdx.x * 256 + threadIdx.x; i < E; i += stride)
    atomicAdd(&lh[dst[i] >> BSH], 1);
  __syncthreads();
  if (threadIdx.x < NB && lh[threadIdx.x]) atomicAdd(&bcnt[threadIdx.x], lh[threadIdx.x]);
}

__global__ void k_bscan(const int* __restrict__ bcnt, int* __restrict__ bbase,
                        int* __restrict__ bcur, unsigned* __restrict__ scal, int NB) {
  __shared__ int s[256];
  int t = threadIdx.x;
  int v = (t < NB) ? bcnt[t] : 0;
  s[t] = v;
  __syncthreads();
  for (int o = 1; o < 256; o <<= 1) {
    int add = (t >= o) ? s[t - o] : 0;
    __syncthreads();
    s[t] += add;
    __syncthreads();
  }
  int excl = s[t] - v;
  if (t < NB) { bbase[t] = excl; bcur[t] = excl; }
  if (t == 0) { scal[0] = 0u; scal[1] = 0u; }
}

// pack = (dst&511)<<17 | src  (requires N <= 2^17)
__global__ __launch_bounds__(256)
void k_bpart(const int* __restrict__ src, const int* __restrict__ dst,
             int* __restrict__ bcur, unsigned* __restrict__ epart, int E, int NB) {
  __shared__ int lh[256];
  __shared__ int gbase[256];
  long base = (long)blockIdx.x * PCHUNK;
  lh[threadIdx.x] = 0;
  __syncthreads();
  int ed[PEPT]; int es[PEPT]; unsigned short lpos[PEPT];
#pragma unroll
  for (int j = 0; j < PEPT; j++) {
    long i = base + threadIdx.x + (long)j * 256;   // coalesced
    if (i < E) {
      int d = dst[i];
      es[j] = src[i];
      ed[j] = d;
      lpos[j] = (unsigned short)atomicAdd(&lh[d >> BSH], 1);
    } else {
      ed[j] = -1;
    }
  }
  __syncthreads();
  if (threadIdx.x < NB) {
    int c = lh[threadIdx.x];
    gbase[threadIdx.x] = c ? atomicAdd(&bcur[threadIdx.x], c) : 0;
  }
  __syncthreads();
#pragma unroll
  for (int j = 0; j < PEPT; j++) {
    int d = ed[j];
    if (d >= 0) {
      unsigned p = (unsigned)(gbase[d >> BSH] + (int)lpos[j]);
      epart[p] = ((unsigned)(d & (BNODES - 1)) << 17) | (unsigned)es[j];
    }
  }
}

// one block per bucket: per-node hist + scan -> deg/rowptr/dinv, scatter col
__global__ __launch_bounds__(256)
void k_fine(const unsigned* __restrict__ epart, const int* __restrict__ bbase,
            const int* __restrict__ bcnt, int* __restrict__ rowptr,
            int* __restrict__ deg, float* __restrict__ dinv,
            int* __restrict__ col, int N) {
  __shared__ int lh[BNODES];
  __shared__ int lexcl[BNODES];
  __shared__ int ssc[256];
  int b = blockIdx.x;
  int base = bbase[b], cnt = bcnt[b];
  int nlo = b << BSH;
  int t = threadIdx.x;
  lh[t] = 0; lh[t + 256] = 0;
  __syncthreads();
  for (int i = t; i < cnt; i += 256) {
    unsigned e = epart[base + i];
    atomicAdd(&lh[e >> 17], 1);
  }
  __syncthreads();
  int a0 = lh[2 * t], a1 = lh[2 * t + 1];
  ssc[t] = a0 + a1;
  __syncthreads();
  for (int o = 1; o < 256; o <<= 1) {
    int add = (t >= o) ? ssc[t - o] : 0;
    __syncthreads();
    ssc[t] += add;
    __syncthreads();
  }
  int excl = ssc[t] - (a0 + a1);
  lexcl[2 * t] = excl;
  lexcl[2 * t + 1] = excl + a0;
  __syncthreads();
#pragma unroll
  for (int k = 0; k < 2; k++) {
    int i = t + k * 256;
    int v = nlo + i;
    if (v < N) {
      int dgv = lh[i];
      deg[v] = dgv;
      rowptr[v] = base + lexcl[i];
      dinv[v] = rsqrtf((float)(dgv + 1));
    }
  }
  __syncthreads();
  lh[2 * t] = lexcl[2 * t];
  lh[2 * t + 1] = lexcl[2 * t + 1];
  __syncthreads();
  for (int i = t; i < cnt; i += 256) {
    unsigned e = epart[base + i];
    int p = atomicAdd(&lh[e >> 17], 1);
    col[base + p] = (int)(e & 0x1FFFFu);
  }
}

// ---------- gemm1: x[Nx256] @ W1[256x32], scaled by dinv ----------
// R7: cooperative coalesced staging of x into LDS (double-buffered, prefetch
// overlapped), compute fed from LDS. Fixed the L1-thrash of per-lane-row x
// loads (R4-R6 asymptote ~56us). 256 thr, 128 rows/block, C=8 x R=2 per
// thread, Kc=16, LDS 48KB -> 3 blocks/CU. x slots XOR-swizzled.
__global__ __launch_bounds__(256)
void k_gemm1(const float* __restrict__ in, const float* __restrict__ W,
             const float* __restrict__ dinv, float* __restrict__ out, int N) {
  __shared__ float Wl[256 * 32];          // 32 KB
  __shared__ float xb[2][128 * 16];       // 2 x 8 KB
  const int t = threadIdx.x;

  // ---- stage W (once), coalesced float4 ----
  {
    const float4* W4 = (const float4*)W;
    float4* Wl4 = (float4*)Wl;
#pragma unroll
    for (int i = 0; i < 8; i++) Wl4[t + i * 256] = W4[t + i * 256];
  }

  // staging ids: 2 threads per row, 2 float4 (= 2 swizzled quads) each
  const int srow = t >> 1;                // 0..127
  const int part = t & 1;
  const int sk = (srow >> 1) & 3;         // swizzle key for this row
  long grow = (long)blockIdx.x * 128 + srow;
  const float* gsrc = in + (grow < (long)N ? grow : (long)(N - 1)) * 256 + part * 8;
  const int q0 = part * 2, q1 = part * 2 + 1;
  const int ws0 = srow * 16 + ((q0 ^ sk) << 2);
  const int ws1 = srow * 16 + ((q1 ^ sk) << 2);

  // compute ids: 4 col-groups x 64 row-groups, rows rg and rg+64
  const int cg = t & 3;
  const int rg = t >> 2;                  // 0..63
  const int c0 = cg * 8;
  const int rk = (rg >> 1) & 3;           // rows rg, rg+64 share key (64/2 %4==0)

  // ---- stage chunk 0 ----
  {
    float4 a = *(const float4*)(gsrc + 0);
    float4 b = *(const float4*)(gsrc + 4);
    *(float4*)&xb[0][ws0] = a;
    *(float4*)&xb[0][ws1] = b;
  }
  __syncthreads();

  float acc[2][8];
#pragma unroll
  for (int i = 0; i < 2; i++)
#pragma unroll
    for (int c = 0; c < 8; c++) acc[i][c] = 0.f;

  for (int ch = 0; ch < 16; ch++) {
    float4 na, nb;
    if (ch < 15) {                        // prefetch next chunk into regs
      na = *(const float4*)(gsrc + (ch + 1) * 16 + 0);
      nb = *(const float4*)(gsrc + (ch + 1) * 16 + 4);
    }
    const float* xc = xb[ch & 1];
#pragma unroll
    for (int q = 0; q < 4; q++) {
      float4 xv0 = *(const float4*)&xc[rg * 16 + ((q ^ rk) << 2)];
      float4 xv1 = *(const float4*)&xc[(rg + 64) * 16 + ((q ^ rk) << 2)];
#pragma unroll
      for (int jj = 0; jj < 4; jj++) {
        const float* wr = &Wl[(ch * 16 + q * 4 + jj) * 32 + c0];
        float4 wa = *(const float4*)(wr);
        float4 wb = *(const float4*)(wr + 4);
        float x0 = f4get(xv0, jj);
        float x1 = f4get(xv1, jj);
        acc[0][0] = fmaf(x0, wa.x, acc[0][0]);
        acc[0][1] = fmaf(x0, wa.y, acc[0][1]);
        acc[0][2] = fmaf(x0, wa.z, acc[0][2]);
        acc[0][3] = fmaf(x0, wa.w, acc[0][3]);
        acc[0][4] = fmaf(x0, wb.x, acc[0][4]);
        acc[0][5] = fmaf(x0, wb.y, acc[0][5]);
        acc[0][6] = fmaf(x0, wb.z, acc[0][6]);
        acc[0][7] = fmaf(x0, wb.w, acc[0][7]);
        acc[1][0] = fmaf(x1, wa.x, acc[1][0]);
        acc[1][1] = fmaf(x1, wa.y, acc[1][1]);
        acc[1][2] = fmaf(x1, wa.z, acc[1][2]);
        acc[1][3] = fmaf(x1, wa.w, acc[1][3]);
        acc[1][4] = fmaf(x1, wb.x, acc[1][4]);
        acc[1][5] = fmaf(x1, wb.y, acc[1][5]);
        acc[1][6] = fmaf(x1, wb.z, acc[1][6]);
        acc[1][7] = fmaf(x1, wb.w, acc[1][7]);
      }
    }
    if (ch < 15) {
      __syncthreads();                    // readers of target buffer done
      float* xn = xb[(ch + 1) & 1];
      *(float4*)&xn[ws0] = na;
      *(float4*)&xn[ws1] = nb;
      __syncthreads();                    // writes visible before compute
    }
  }

  // ---- epilogue: scale by dinv, store ----
#pragma unroll
  for (int i = 0; i < 2; i++) {
    long r = (long)blockIdx.x * 128 + rg + i * 64;
    if (r < (long)N) {
      float dv = dinv[r];
      float* op = &out[r * 32 + c0];
      *(float4*)(op) = make_float4(acc[i][0] * dv, acc[i][1] * dv,
                                   acc[i][2] * dv, acc[i][3] * dv);
      *(float4*)(op + 4) = make_float4(acc[i][4] * dv, acc[i][5] * dv,
                                       acc[i][6] * dv, acc[i][7] * dv);
    }
  }
}

// ---------- fused MLP head: s2[Nx32] -> logits[Nx64] ----------
// R8: fuses z2=relu(s2@W2+b2); t=relu(z2@Wo1+bo1); logits=t@Wo2+bo2 (+max)
// into one kernel. Kills z2/t HBM round-trips (~100MB) and 2 launches.
// 256 thr: 8 col-groups x 32 row-groups x ROWS=4 -> 128 rows/block.
// LDS: A 16KB (W2 stage1, Wo2 stage3), B 16KB (Wo1), xr 32KB (row exchange,
// XOR quad-swizzle q^=rg&7 + phys row rg+32i: conflict-free reads; row
// stride 64 floats == 0 mod 32 banks would be 8-way otherwise). 64KB total
// -> 2 blocks/CU.
__global__ __launch_bounds__(256)
void k_head(const float* __restrict__ s2,
            const float* __restrict__ W2, const float* __restrict__ b2,
            const float* __restrict__ Wo1, const float* __restrict__ bo1,
            const float* __restrict__ Wo2, const float* __restrict__ bo2,
            float* __restrict__ out, int N, unsigned* __restrict__ gmax) {
  __shared__ float A[64 * 64];        // W2 (2048 used) then Wo2 (4096)
  __shared__ float B[64 * 64];        // Wo1
  __shared__ float xr[128 * 64];      // row exchange (z2, then t); swizzled
  const int t = threadIdx.x;
  const int cg = t & 7, rg = t >> 3;  // 8 col-groups, 32 row-groups
  const int c0 = cg * 8;
  const int key = rg & 7;             // quad-swizzle key (distinct per wave lane-group)
  const long r0 = (long)blockIdx.x * 128 + rg * 4;

  {  // stage W2 -> A (2048 floats), Wo1 -> B (4096 floats)
    const float4* w2 = (const float4*)W2;
    const float4* w1 = (const float4*)Wo1;
    float4* Af = (float4*)A;
    float4* Bf = (float4*)B;
    Af[t] = w2[t];
    Af[t + 256] = w2[t + 256];
#pragma unroll
    for (int i = 0; i < 4; i++) Bf[t + i * 256] = w1[t + i * 256];
  }
  __syncthreads();

  bool rv[4];
  int xrow[4];
#pragma unroll
  for (int i = 0; i < 4; i++) {
    rv[i] = (r0 + i) < (long)N;
    xrow[i] = (rg + 32 * i) * 64;     // phys row base (floats)
  }

  float acc[4][8];

  // ---- stage 1: z2 = relu(s2 @ W2 + b2) -> xr ----
#pragma unroll
  for (int i = 0; i < 4; i++)
#pragma unroll
    for (int c = 0; c < 8; c++) acc[i][c] = 0.f;
  {
    const float* ip = s2 + r0 * 32;
#pragma unroll 2
    for (int k = 0; k < 32; k += 4) {
      float4 xv[4];
#pragma unroll
      for (int i = 0; i < 4; i++)
        xv[i] = rv[i] ? *(const float4*)(ip + i * 32 + k)
                      : make_float4(0.f, 0.f, 0.f, 0.f);
#pragma unroll
      for (int jj = 0; jj < 4; jj++) {
        float4 wa = *(const float4*)&A[(k + jj) * 64 + c0];
        float4 wb = *(const float4*)&A[(k + jj) * 64 + c0 + 4];
#pragma unroll
        for (int i = 0; i < 4; i++) {
          float xs = f4get(xv[i], jj);
          acc[i][0] = fmaf(xs, wa.x, acc[i][0]);
          acc[i][1] = fmaf(xs, wa.y, acc[i][1]);
          acc[i][2] = fmaf(xs, wa.z, acc[i][2]);
          acc[i][3] = fmaf(xs, wa.w, acc[i][3]);
          acc[i][4] = fmaf(xs, wb.x, acc[i][4]);
          acc[i][5] = fmaf(xs, wb.y, acc[i][5]);
          acc[i][6] = fmaf(xs, wb.z, acc[i][6]);
          acc[i][7] = fmaf(xs, wb.w, acc[i][7]);
        }
      }
    }
    float bo[8];
#pragma unroll
    for (int c = 0; c < 8; c++) bo[c] = b2[c0 + c];
    const int q0 = (2 * cg) ^ key, q1 = (2 * cg + 1) ^ key;
#pragma unroll
    for (int i = 0; i < 4; i++) {
      float v0 = fmaxf(acc[i][0] + bo[0], 0.f);
      float v1 = fmaxf(acc[i][1] + bo[1], 0.f);
      float v2 = fmaxf(acc[i][2] + bo[2], 0.f);
      float v3 = fmaxf(acc[i][3] + bo[3], 0.f);
      float v4 = fmaxf(acc[i][4] + bo[4], 0.f);
      float v5 = fmaxf(acc[i][5] + bo[5], 0.f);
      float v6 = fmaxf(acc[i][6] + bo[6], 0.f);
      float v7 = fmaxf(acc[i][7] + bo[7], 0.f);
      *(float4*)&xr[xrow[i] + 4 * q0] = make_float4(v0, v1, v2, v3);
      *(float4*)&xr[xrow[i] + 4 * q1] = make_float4(v4, v5, v6, v7);
    }
  }
  __syncthreads();

  // prefetch Wo2 into regs (hidden under stage 2)
  float4 wo2r[4];
  {
    const float4* w = (const float4*)Wo2;
#pragma unroll
    for (int i = 0; i < 4; i++) wo2r[i] = w[t + i * 256];
  }

  // ---- stage 2: tt = relu(z2 @ Wo1 + bo1) ----
#pragma unroll
  for (int i = 0; i < 4; i++)
#pragma unroll
    for (int c = 0; c < 8; c++) acc[i][c] = 0.f;
#pragma unroll 2
  for (int k = 0; k < 64; k += 4) {
    const int q = k >> 2;
    float4 xv[4];
#pragma unroll
    for (int i = 0; i < 4; i++)
      xv[i] = *(const float4*)&xr[xrow[i] + 4 * (q ^ key)];
#pragma unroll
    for (int jj = 0; jj < 4; jj++) {
      float4 wa = *(const float4*)&B[(k + jj) * 64 + c0];
      float4 wb = *(const float4*)&B[(k + jj) * 64 + c0 + 4];
#pragma unroll
      for (int i = 0; i < 4; i++) {
        float xs = f4get(xv[i], jj);
        acc[i][0] = fmaf(xs, wa.x, acc[i][0]);
        acc[i][1] = fmaf(xs, wa.y, acc[i][1]);
        acc[i][2] = fmaf(xs, wa.z, acc[i][2]);
        acc[i][3] = fmaf(xs, wa.w, acc[i][3]);
        acc[i][4] = fmaf(xs, wb.x, acc[i][4]);
        acc[i][5] = fmaf(xs, wb.y, acc[i][5]);
        acc[i][6] = fmaf(xs, wb.z, acc[i][6]);
        acc[i][7] = fmaf(xs, wb.w, acc[i][7]);
      }
    }
  }
  __syncthreads();                    // all z2 reads done; A free, xr free

  {  // Wo2 regs -> A; t (relu+bo1) -> xr
    float4* Af = (float4*)A;
#pragma unroll
    for (int i = 0; i < 4; i++) Af[t + i * 256] = wo2r[i];
    float bo[8];
#pragma unroll
    for (int c = 0; c < 8; c++) bo[c] = bo1[c0 + c];
    const int q0 = (2 * cg) ^ key, q1 = (2 * cg + 1) ^ key;
#pragma unroll
    for (int i = 0; i < 4; i++) {
      float v0 = fmaxf(acc[i][0] + bo[0], 0.f);
      float v1 = fmaxf(acc[i][1] + bo[1], 0.f);
      float v2 = fmaxf(acc[i][2] + bo[2], 0.f);
      float v3 = fmaxf(acc[i][3] + bo[3], 0.f);
      float v4 = fmaxf(acc[i][4] + bo[4], 0.f);
      float v5 = fmaxf(acc[i][5] + bo[5], 0.f);
      float v6 = fmaxf(acc[i][6] + bo[6], 0.f);
      float v7 = fmaxf(acc[i][7] + bo[7], 0.f);
      *(float4*)&xr[xrow[i] + 4 * q0] = make_float4(v0, v1, v2, v3);
      *(float4*)&xr[xrow[i] + 4 * q1] = make_float4(v4, v5, v6, v7);
    }
  }
  __syncthreads();

  // ---- stage 3: logits = tt @ Wo2 + bo2; track max ----
#pragma unroll
  for (int i = 0; i < 4; i++)
#pragma unroll
    for (int c = 0; c < 8; c++) acc[i][c] = 0.f;
#pragma unroll 2
  for (int k = 0; k < 64; k += 4) {
    const int q = k >> 2;
    float4 xv[4];
#pragma unroll
    for (int i = 0; i < 4; i++)
      xv[i] = *(const float4*)&xr[xrow[i] + 4 * (q ^ key)];
#pragma unroll
    for (int jj = 0; jj < 4; jj++) {
      float4 wa = *(const float4*)&A[(k + jj) * 64 + c0];
      float4 wb = *(const float4*)&A[(k + jj) * 64 + c0 + 4];
#pragma unroll
      for (int i = 0; i < 4; i++) {
        float xs = f4get(xv[i], jj);
        acc[i][0] = fmaf(xs, wa.x, acc[i][0]);
        acc[i][1] = fmaf(xs, wa.y, acc[i][1]);
        acc[i][2] = fmaf(xs, wa.z, acc[i][2]);
        acc[i][3] = fmaf(xs, wa.w, acc[i][3]);
        acc[i][4] = fmaf(xs, wb.x, acc[i][4]);
        acc[i][5] = fmaf(xs, wb.y, acc[i][5]);
        acc[i][6] = fmaf(xs, wb.z, acc[i][6]);
        acc[i][7] = fmaf(xs, wb.w, acc[i][7]);
      }
    }
  }
  float m = -3.4e38f;
  {
    float bo[8];
#pragma unroll
    for (int c = 0; c < 8; c++) bo[c] = bo2[c0 + c];
#pragma unroll
    for (int i = 0; i < 4; i++) {
      if (!rv[i]) continue;
      float o[8];
#pragma unroll
      for (int c = 0; c < 8; c++) {
        float v = acc[i][c] + bo[c];
        m = fmaxf(m, v);
        o[c] = v;
      }
      float* op = &out[(r0 + i) * 64 + c0];
      *(float4*)(op) = make_float4(o[0], o[1], o[2], o[3]);
      *(float4*)(op + 4) = make_float4(o[4], o[5], o[6], o[7]);
    }
  }
  // block max reduce via xr (free now)
  __syncthreads();
  xr[t] = m;
  __syncthreads();
  for (int o2 = 128; o2 > 0; o2 >>= 1) {
    if (t < o2) xr[t] = fmaxf(xr[t], xr[t + o2]);
    __syncthreads();
  }
  if (t == 0) atomicMax(gmax, fkey(xr[0]));
}

// ---------- GCN aggregation (float4 lanes) ----------
template <int FEAT, bool BIAS, bool RELU, bool PSCALE>
__launch_bounds__(256)
__global__ void k_aggv(const float* __restrict__ g, const int* __restrict__ col,
                       const int* __restrict__ rowptr, const int* __restrict__ deg,
                       const float* __restrict__ dinv, const float* __restrict__ bias,
                       float* __restrict__ out, int N) {
  constexpr int LPN = FEAT / 4;       // lanes per node (float4 each)
  constexpr int NPB = 256 / LPN;      // nodes per block
  int nib = threadIdx.x / LPN;
  int c = threadIdx.x % LPN;
  long v = (long)blockIdx.x * NPB + nib;
  if (v >= N) return;

  const float4* g4 = (const float4*)g;
  float4 acc = g4[v * LPN + c];       // self-loop term
  int start = rowptr[v], dg = deg[v];
  int e = 0;
  while (e < dg) {
    int cnt = min(LPN, dg - e);
    int idx = (c < cnt) ? col[start + e + c] : 0;
    int j = 0;
    for (; j + 4 <= cnt; j += 4) {    // 4 independent 16B gathers in flight
      int u0 = __shfl(idx, j + 0, LPN);
      int u1 = __shfl(idx, j + 1, LPN);
      int u2 = __shfl(idx, j + 2, LPN);
      int u3 = __shfl(idx, j + 3, LPN);
      float4 a0 = g4[(long)u0 * LPN + c];
      float4 a1 = g4[(long)u1 * LPN + c];
      float4 a2 = g4[(long)u2 * LPN + c];
      float4 a3 = g4[(long)u3 * LPN + c];
      acc.x += (a0.x + a1.x) + (a2.x + a3.x);
      acc.y += (a0.y + a1.y) + (a2.y + a3.y);
      acc.z += (a0.z + a1.z) + (a2.z + a3.z);
      acc.w += (a0.w + a1.w) + (a2.w + a3.w);
    }
    for (; j < cnt; j++) {
      int u = __shfl(idx, j, LPN);
      float4 a = g4[(long)u * LPN + c];
      acc.x += a.x; acc.y += a.y; acc.z += a.z; acc.w += a.w;
    }
    e += cnt;
  }
  float dv = dinv[v];
  float4 val;
  val.x = acc.x * dv; val.y = acc.y * dv; val.z = acc.z * dv; val.w = acc.w * dv;
  if (BIAS) {
    float4 b = ((const float4*)bias)[c];
    val.x += b.x; val.y += b.y; val.z += b.z; val.w += b.w;
  }
  if (RELU) {
    val.x = fmaxf(val.x, 0.f); val.y = fmaxf(val.y, 0.f);
    val.z = fmaxf(val.z, 0.f); val.w = fmaxf(val.w, 0.f);
  }
  if (PSCALE) {
    val.x *= dv; val.y *= dv; val.z *= dv; val.w *= dv;
  }
  ((float4*)out)[v * LPN + c] = val;
}

// ---------- softmax ----------
__global__ void k_smsum(const float* __restrict__ logit, unsigned* __restrict__ scal, int total) {
  __shared__ float s[256];
  float gmax = funkey(scal[0]);
  float loc = 0.f;
  for (int i = blockIdx.x * 256 + threadIdx.x; i < total; i += gridDim.x * 256)
    loc += expf(logit[i] - gmax);
  s[threadIdx.x] = loc; __syncthreads();
  for (int o = 128; o > 0; o >>= 1) {
    if (threadIdx.x < o) s[threadIdx.x] += s[threadIdx.x + o];
    __syncthreads();
  }
  if (threadIdx.x == 0) atomicAdd((float*)&scal[1], s[0]);
}

__global__ void k_smnorm(float* __restrict__ logit, const unsigned* __restrict__ scal, int total) {
  float gmax = funkey(scal[0]);
  float inv = 1.0f / __uint_as_float(scal[1]);
  int i = blockIdx.x * 256 + threadIdx.x;
  if (i < total) logit[i] = expf(logit[i] - gmax) * inv;
}

// ---------- launch ----------
extern "C" void kernel_launch(void* const* d_in, const int* in_sizes, int n_in,
                              void* d_out, int out_size, void* d_ws, size_t ws_size,
                              hipStream_t stream) {
  const float* x   = (const float*)d_in[0];
  const int*   ei  = (const int*)d_in[1];
  const float* W1  = (const float*)d_in[3];
  const float* b1  = (const float*)d_in[4];
  const float* W2  = (const float*)d_in[5];
  const float* b2  = (const float*)d_in[6];
  const float* Wo1 = (const float*)d_in[7];
  const float* bo1 = (const float*)d_in[8];
  const float* Wo2 = (const float*)d_in[9];
  const float* bo2 = (const float*)d_in[10];

  const int N = in_sizes[0] / 256;   // in_dim = 256
  const int E = in_sizes[1] / 2;
  const int* src = ei;
  const int* dst = ei + E;
  const int NB = (N + BNODES - 1) / BNODES;

  size_t o = 0;
  auto carve = [&](size_t bytes) -> char* {
    char* p = (char*)d_ws + o;
    o += (bytes + 255) & ~(size_t)255;
    return p;
  };
  float* R1     = (float*)carve((size_t)N * 64 * 4);  // g1 | s2
  float* R2     = (float*)carve((size_t)N * 64 * 4);  // epart | p
  int*   col    = (int*)carve((size_t)E * 4);
  int*   deg    = (int*)carve((size_t)N * 4);
  float* dinv   = (float*)carve((size_t)N * 4);
  int*   rowptr = (int*)carve((size_t)N * 4);
  int*   bcnt   = (int*)carve(256 * 4);
  int*   bbase  = (int*)carve(256 * 4);
  int*   bcur   = (int*)carve(256 * 4);
  unsigned* scal = (unsigned*)carve(64);

  unsigned* epart = (unsigned*)R2;  // dead before p is written
  float* g1 = R1;   // N x 32
  float* p  = R2;   // N x 32: dinv .* relu(layer-1 out)
  float* s2 = R1;   // N x 32: aggregated p (g1 dead)
  float* logits = (float*)d_out;

  // ---- CSR build ----
  k_binit<<<1, 256, 0, stream>>>(bcnt);
  k_bcount<<<512, 256, 0, stream>>>(dst, bcnt, E, NB);
  k_bscan<<<1, 256, 0, stream>>>(bcnt, bbase, bcur, scal, NB);
  k_bpart<<<(E + PCHUNK - 1) / PCHUNK, 256, 0, stream>>>(src, dst, bcur, epart, E, NB);
  k_fine<<<NB, 256, 0, stream>>>(epart, bbase, bcnt, rowptr, deg, dinv, col, N);

  const int g1G = (N + 127) / 128;  // gemm1 / head: 128 rows per block
  const int gA = (N + 31) / 32;     // agg32: 32 nodes per block

  // layer 1: g1 = dinv .* (x @ W1); p = dinv .* relu(b1 + dinv*(g1[v]+sum g1[u]))
  k_gemm1<<<g1G, 256, 0, stream>>>(x, W1, dinv, g1, N);
  k_aggv<32, true, true, true><<<gA, 256, 0, stream>>>(g1, col, rowptr, deg, dinv, b1, p, N);

  // layer 2 (aggregation commuted before W2): s2 = dinv*(p[v]+sum p[u])
  k_aggv<32, false, false, false><<<gA, 256, 0, stream>>>(p, col, rowptr, deg, dinv, nullptr, s2, N);

  // fused MLP head: s2 -> logits (tracks global max in scal[0])
  k_head<<<g1G, 256, 0, stream>>>(s2, W2, b2, Wo1, bo1, Wo2, bo2, logits, N, scal);

  // softmax over all N*64 logits
  k_smsum<<<1024, 256, 0, stream>>>(logits, scal, out_size);
  k_smnorm<<<(out_size + 255) / 256, 256, 0, stream>>>(logits, scal, out_size);
}